// Round 8
// baseline (1890.444 us; speedup 1.0000x reference)
//
#include <hip/hip_runtime.h>

constexpr int B = 4, T = 8, N = 4096, C0 = 64, C1 = 128;
constexpr int M = 1024, KNN = 32;

typedef __attribute__((ext_vector_type(8))) short short8;
typedef __attribute__((ext_vector_type(4))) float f32x4;

__device__ __forceinline__ unsigned short f2bf(float x) {
  unsigned u = __float_as_uint(x);
  u = u + 0x7FFFu + ((u >> 16) & 1u);
  return (unsigned short)(u >> 16);
}
__device__ __forceinline__ float bf2f(unsigned short h) {
  return __uint_as_float((unsigned)h << 16);
}

template <int CTRL>
__device__ __forceinline__ float dppf(float x) {
  return __int_as_float(__builtin_amdgcn_update_dpp(0, __float_as_int(x), CTRL, 0xF, 0xF, true));
}
template <int CTRL>
__device__ __forceinline__ int dppi(int x) {
  return __builtin_amdgcn_update_dpp(0, x, CTRL, 0xF, 0xF, true);
}
template <int CTRL>
__device__ __forceinline__ unsigned long long dppu64(unsigned long long x) {
  unsigned lo = (unsigned)dppi<CTRL>((int)(unsigned)x);
  unsigned hi = (unsigned)dppi<CTRL>((int)(unsigned)(x >> 32));
  return ((unsigned long long)hi << 32) | lo;
}
__device__ __forceinline__ void kmerge(unsigned long long& a, unsigned long long b) {
  if (b > a) a = b;
}
__device__ __forceinline__ unsigned long long kmax(unsigned long long a, unsigned long long b) {
  return b > a ? b : a;
}

// ---------------- prep: WfT[c][o] = Wf[o][c] --------------------------------
__global__ __launch_bounds__(256) void prep_wft(const float* __restrict__ Wf,
                                                float* __restrict__ WfT) {
  int t = blockIdx.x * 256 + threadIdx.x;
  if (t < 64 * 64) WfT[t] = Wf[(t & 63) * 64 + (t >> 6)];
}

// ---------------- prep: W1 -> MFMA A-fragment-ordered bf16 hi/lo ------------
__global__ __launch_bounds__(256) void prep_w1frag(const float* __restrict__ W1,
                                                   unsigned short* __restrict__ w1hi,
                                                   unsigned short* __restrict__ w1lo) {
  int t = blockIdx.x * 256 + threadIdx.x;
  if (t >= 8192) return;
  int j = t & 7, lane = (t >> 3) & 63, mt = (t >> 9) & 7, kt = t >> 12;
  int row = mt * 16 + (lane & 15);
  int k = kt * 32 + (lane >> 4) * 8 + j;
  float v = W1[row * 64 + k];
  unsigned short hi = f2bf(v);
  w1hi[t] = hi;
  w1lo[t] = f2bf(v - bf2f(hi));
}

// ---------------- fps phase body: iterations [sBeg, sEnd) -------------------
// State persisted in ws between phases: D per point + last pick index.
__device__ void fps_phase(char* smem, const float* __restrict__ xyz,
                          float* __restrict__ out_xyz, float* __restrict__ wsD,
                          int* __restrict__ wsLast, int bt, int sBeg, int sEnd) {
  float4* P4 = (float4*)smem;                                              // 64 KB
  int* pick_l = (int*)(smem + 65536);                                      // 4 KB
  unsigned long long* wslot = (unsigned long long*)(smem + 65536 + 4096);  // 256 B
  const float* p = xyz + (size_t)bt * N * 3;
  int tid = threadIdx.x;
  int lane = tid & 63, w = tid >> 6;
  for (int i = tid; i < N; i += 256)
    P4[i] = make_float4(p[i * 3 + 0], p[i * 3 + 1], p[i * 3 + 2], 0.f);
  if (sBeg == 1 && tid == 0) pick_l[0] = 0;
  __syncthreads();
  float X[16], Y[16], Z[16], D[16];
  unsigned inv[16];
#pragma unroll
  for (int j = 0; j < 16; ++j) {
    float4 v = P4[j * 256 + tid];
    X[j] = v.x; Y[j] = v.y; Z[j] = v.z;
    inv[j] = ~(unsigned)(j * 256 + tid);
  }
  int lidx;
  if (sBeg == 1) {
#pragma unroll
    for (int j = 0; j < 16; ++j) D[j] = 1e10f;
    lidx = 0;
  } else {
#pragma unroll
    for (int j = 0; j < 16; ++j) D[j] = wsD[bt * N + j * 256 + tid];
    lidx = wsLast[bt];
  }
  for (int s = sBeg; s < sEnd; ++s) {
    float4 lp = P4[lidx];  // broadcast ds_read_b128
    unsigned long long k[16];
#pragma unroll
    for (int j = 0; j < 16; ++j) {
      float dx = __fsub_rn(X[j], lp.x);
      float dy = __fsub_rn(Y[j], lp.y);
      float dz = __fsub_rn(Z[j], lp.z);
      float d = __fadd_rn(__fadd_rn(__fmul_rn(dx, dx), __fmul_rn(dy, dy)), __fmul_rn(dz, dz));
      float nd = fminf(D[j], d);
      D[j] = nd;
      k[j] = ((unsigned long long)__float_as_uint(nd) << 32) | inv[j];
    }
#pragma unroll
    for (int st = 8; st >= 1; st >>= 1)
#pragma unroll
      for (int j = 0; j < st; ++j) kmerge(k[j], k[j + st]);
    unsigned long long best = k[0];
    kmerge(best, dppu64<0xB1>(best));
    kmerge(best, dppu64<0x4E>(best));
    kmerge(best, dppu64<0x141>(best));
    kmerge(best, dppu64<0x140>(best));
    int buf = s & 1;
    if ((lane & 15) == 0) wslot[buf * 16 + w * 4 + (lane >> 4)] = best;
    __syncthreads();
    const ulonglong2* ws2 = (const ulonglong2*)&wslot[buf * 16];
    ulonglong2 a0 = ws2[0], a1 = ws2[1], a2 = ws2[2], a3 = ws2[3];
    ulonglong2 a4 = ws2[4], a5 = ws2[5], a6 = ws2[6], a7 = ws2[7];
    unsigned long long t0 = kmax(kmax(a0.x, a0.y), kmax(a1.x, a1.y));
    unsigned long long t1 = kmax(kmax(a2.x, a2.y), kmax(a3.x, a3.y));
    unsigned long long t2 = kmax(kmax(a4.x, a4.y), kmax(a5.x, a5.y));
    unsigned long long t3 = kmax(kmax(a6.x, a6.y), kmax(a7.x, a7.y));
    unsigned long long g = kmax(kmax(t0, t1), kmax(t2, t3));
    lidx = (int)(~(unsigned)g);
    if (tid == 0) pick_l[s] = lidx;
  }
  __syncthreads();
  if (sBeg == 1) {
    // persist state for phase B
#pragma unroll
    for (int j = 0; j < 16; ++j) wsD[bt * N + j * 256 + tid] = D[j];
    if (tid == 0) wsLast[bt] = lidx;
  }
  int mBeg = (sBeg == 1) ? 0 : sBeg;
  float* outp = out_xyz + (size_t)bt * M * 3;
  for (int mm = mBeg + tid; mm < sEnd; mm += 256) {
    float4 v = P4[pick_l[mm]];
    outp[mm * 3 + 0] = v.x;
    outp[mm * 3 + 1] = v.y;
    outp[mm * 3 + 2] = v.z;
  }
}

__device__ void rff_body(char* smem, const float* __restrict__ f,
                         const float* __restrict__ WfT, float* __restrict__ RFF, int rid) {
  float (*tile)[65] = (float (*)[65])smem;  // 64x65 f32 = 16.6 KB
  int bt = rid >> 6;
  int n0 = (rid & 63) * 64;
  const float* src = f + (size_t)bt * C0 * N;
  int tx = threadIdx.x & 63, ty = threadIdx.x >> 6;
  for (int r = ty; r < 64; r += 4)
    tile[r][tx] = src[(size_t)r * N + n0 + tx];
  __syncthreads();
  float acc[16];
#pragma unroll
  for (int oo = 0; oo < 16; ++oo) acc[oo] = 0.f;
  int obase = ty * 16;
#pragma unroll 4
  for (int c = 0; c < 64; ++c) {
    float fv = tile[c][tx];
    const float* wr = WfT + c * 64 + obase;
#pragma unroll
    for (int oo = 0; oo < 16; ++oo) acc[oo] = fmaf(fv, wr[oo], acc[oo]);
  }
  __syncthreads();
#pragma unroll
  for (int oo = 0; oo < 16; ++oo) tile[obase + oo][tx] = fmaxf(acc[oo], 0.f);
  __syncthreads();
  float* dst = RFF + ((size_t)bt * N + n0) * 64;
  for (int r = ty; r < 64; r += 4)
    dst[(size_t)r * 64 + tx] = tile[tx][r];
}

// phase A (iters 1..511) fused with rff
__global__ __launch_bounds__(256) void fps_rff_a_kernel(const float* __restrict__ xyz,
                                                        float* __restrict__ out_xyz,
                                                        const float* __restrict__ feats,
                                                        const float* __restrict__ WfT,
                                                        float* __restrict__ RFF,
                                                        float* __restrict__ wsD,
                                                        int* __restrict__ wsLast) {
  __shared__ __align__(16) char smem[65536 + 4096 + 256];
  if (blockIdx.x < 32)
    fps_phase(smem, xyz, out_xyz, wsD, wsLast, blockIdx.x, 1, 512);
  else
    rff_body(smem, feats, WfT, RFF, blockIdx.x - 32);
}

// phase B (iters 512..1023)
__global__ __launch_bounds__(256) void fps_b_kernel(const float* __restrict__ xyz,
                                                    float* __restrict__ out_xyz,
                                                    float* __restrict__ wsD,
                                                    int* __restrict__ wsLast) {
  __shared__ __align__(16) char smem[65536 + 4096 + 256];
  fps_phase(smem, xyz, out_xyz, wsD, wsLast, blockIdx.x, 512, 1024);
}

// ---------------- ball query: one wave per (b,t,di,m) -----------------------
__global__ __launch_bounds__(256) void ballq_kernel(const float* __restrict__ xyz,
                                                    const float* __restrict__ anchors,
                                                    int* __restrict__ idxbuf) {
  const float R2 = 0.04f;
  int w = threadIdx.x >> 6, lane = threadIdx.x & 63;
  int q = blockIdx.x * 4 + w;
  int m = q & (M - 1);
  int di = (q >> 10) % 3;
  int bt = q / (M * 3);
  int b = bt >> 3, t = bt & 7;
  int srct = t + di - 1;
  srct = srct < 0 ? 0 : (srct > 7 ? 7 : srct);
  const float* anc = anchors + ((size_t)(bt * M + m)) * 3;
  float ax = anc[0], ay = anc[1], az = anc[2];
  const float* pts = xyz + ((size_t)(b * T + srct)) * N * 3;
  int* outp = idxbuf + (size_t)q * KNN;
  int cnt = 0, first = 0;
  for (int c = 0; c < N / 64 && cnt < KNN; ++c) {
    int pi = c * 64 + lane;
    const float* pp = pts + (size_t)pi * 3;
    float dx = __fsub_rn(ax, pp[0]);
    float dy = __fsub_rn(ay, pp[1]);
    float dz = __fsub_rn(az, pp[2]);
    float d2 = __fadd_rn(__fadd_rn(__fmul_rn(dx, dx), __fmul_rn(dy, dy)), __fmul_rn(dz, dz));
    bool hit = d2 < R2;
    unsigned long long mask = __ballot(hit);
    if (cnt == 0 && mask) first = c * 64 + (int)__builtin_ctzll(mask);
    int prefix = (int)__popcll(mask & ((1ull << lane) - 1ull));
    int slot = cnt + prefix;
    if (hit && slot < KNN) outp[slot] = pi;
    cnt += (int)__popcll(mask);
  }
  int cntK = cnt < KNN ? cnt : KNN;
  int fill = (cnt == 0) ? 0 : first;
  if (lane < KNN && lane >= cntK) outp[lane] = fill;
}

// ---------------- fused gather + dfeat + split-bf16 MFMA layer2 (v3) --------
// __launch_bounds__(256,4): force <=128 VGPR / 4 blocks/CU to test the
// occupancy-vs-latency hypothesis; WRITE_SIZE will expose any spill.
__global__ __launch_bounds__(256, 4) void mlp_kernel(const float* __restrict__ xyz,
                                                     const float* __restrict__ RFF,
                                                     const unsigned short* __restrict__ w1hi,
                                                     const unsigned short* __restrict__ w1lo,
                                                     const float* __restrict__ Wd,
                                                     const float* __restrict__ anchors,
                                                     const int* __restrict__ idxbuf,
                                                     float* __restrict__ out_feats) {
  __shared__ unsigned short Ah[8192];
  __shared__ unsigned short Al[8192];
  __shared__ float wd_l[256];
  __shared__ float fstage[4][128];
  int tid = threadIdx.x;
  {
    uint4* dh = (uint4*)Ah;
    const uint4* sh = (const uint4*)w1hi;
    uint4* dl = (uint4*)Al;
    const uint4* sl = (const uint4*)w1lo;
    for (int i = tid; i < 1024; i += 256) { dh[i] = sh[i]; dl[i] = sl[i]; }
    wd_l[tid] = Wd[tid];
  }
  __syncthreads();
  int w = tid >> 6, lane = tid & 63;
  int nloc = lane & 15, grp = lane >> 4;
  int bt = blockIdx.x >> 8;
  int m0 = (blockIdx.x & 255) * 4;
  int m = m0 + w;
  int b = bt >> 3, t = bt & 7;
  int aoff = __builtin_amdgcn_readfirstlane(bt * M + m);
  float ax = anchors[(size_t)aoff * 3 + 0];
  float ay = anchors[(size_t)aoff * 3 + 1];
  float az = anchors[(size_t)aoff * 3 + 2];
  f32x4 acc[8];
#pragma unroll
  for (int mt = 0; mt < 8; ++mt) acc[mt] = (f32x4){0.f, 0.f, 0.f, 0.f};

  for (int di = 0; di < 3; ++di) {
    int srct = t + di - 1;
    srct = srct < 0 ? 0 : (srct > 7 ? 7 : srct);
    const float* rf = RFF + ((size_t)(b * T + srct)) * N * 64;
    const float* pts = xyz + ((size_t)(b * T + srct)) * N * 3;
    const int* ip = idxbuf + ((size_t)((bt * 3 + di) * M + m)) * KNN;
    int n0 = ip[nloc], n1 = ip[16 + nloc];
    float4 g0[2][2], g1[2][2];  // [kt][half] transient
#pragma unroll
    for (int kt = 0; kt < 2; ++kt) {
      const float* r0 = rf + (size_t)n0 * 64 + kt * 32 + grp * 8;
      const float* r1 = rf + (size_t)n1 * 64 + kt * 32 + grp * 8;
      g0[kt][0] = *(const float4*)&r0[0];
      g0[kt][1] = *(const float4*)&r0[4];
      g1[kt][0] = *(const float4*)&r1[0];
      g1[kt][1] = *(const float4*)&r1[4];
    }
    float dx0 = pts[n0 * 3 + 0] - ax, dy0 = pts[n0 * 3 + 1] - ay, dz0 = pts[n0 * 3 + 2] - az;
    float dx1 = pts[n1 * 3 + 0] - ax, dy1 = pts[n1 * 3 + 1] - ay, dz1 = pts[n1 * 3 + 2] - az;
    float tv = (float)(di - 1);
    short8 Bh[2][2], Bl[2][2];  // [kt][nt]
#pragma unroll
    for (int kt = 0; kt < 2; ++kt) {
      short8 bh0, bl0, bh1, bl1;
#pragma unroll
      for (int j = 0; j < 8; ++j) {
        int ch = kt * 32 + grp * 8 + j;
        float4 wr = *(const float4*)&wd_l[ch * 4];
        float dd0 = fmaf(dx0, wr.x, fmaf(dy0, wr.y, fmaf(dz0, wr.z, tv * wr.w)));
        float dd1 = fmaf(dx1, wr.x, fmaf(dy1, wr.y, fmaf(dz1, wr.z, tv * wr.w)));
        const float* gp0 = (const float*)&g0[kt][j >> 2];
        const float* gp1 = (const float*)&g1[kt][j >> 2];
        float h0 = gp0[j & 3] + fmaxf(dd0, 0.f);
        float h1 = gp1[j & 3] + fmaxf(dd1, 0.f);
        unsigned short hi0 = f2bf(h0);
        bh0[j] = (short)hi0;
        bl0[j] = (short)f2bf(h0 - bf2f(hi0));
        unsigned short hi1 = f2bf(h1);
        bh1[j] = (short)hi1;
        bl1[j] = (short)f2bf(h1 - bf2f(hi1));
      }
      Bh[kt][0] = bh0; Bl[kt][0] = bl0;
      Bh[kt][1] = bh1; Bl[kt][1] = bl1;
    }
#pragma unroll
    for (int hf = 0; hf < 2; ++hf) {
      f32x4 c[4][2];
#pragma unroll
      for (int mq = 0; mq < 4; ++mq) {
        c[mq][0] = (f32x4){0.f, 0.f, 0.f, 0.f};
        c[mq][1] = (f32x4){0.f, 0.f, 0.f, 0.f};
      }
#pragma unroll
      for (int kt = 0; kt < 2; ++kt) {
#pragma unroll
        for (int mq = 0; mq < 4; ++mq) {
          int mt = hf * 4 + mq;
          int fo = ((kt * 8 + mt) * 64 + lane) * 8;
          short8 ahf = *(const short8*)&Ah[fo];
          short8 alf = *(const short8*)&Al[fo];
          c[mq][0] = __builtin_amdgcn_mfma_f32_16x16x32_bf16(ahf, Bh[kt][0], c[mq][0], 0, 0, 0);
          c[mq][0] = __builtin_amdgcn_mfma_f32_16x16x32_bf16(ahf, Bl[kt][0], c[mq][0], 0, 0, 0);
          c[mq][0] = __builtin_amdgcn_mfma_f32_16x16x32_bf16(alf, Bh[kt][0], c[mq][0], 0, 0, 0);
          c[mq][1] = __builtin_amdgcn_mfma_f32_16x16x32_bf16(ahf, Bh[kt][1], c[mq][1], 0, 0, 0);
          c[mq][1] = __builtin_amdgcn_mfma_f32_16x16x32_bf16(ahf, Bl[kt][1], c[mq][1], 0, 0, 0);
          c[mq][1] = __builtin_amdgcn_mfma_f32_16x16x32_bf16(alf, Bh[kt][1], c[mq][1], 0, 0, 0);
        }
      }
#pragma unroll
      for (int mq = 0; mq < 4; ++mq)
#pragma unroll
        for (int r = 0; r < 4; ++r) {
          float o = fmaxf(c[mq][0][r], c[mq][1][r]);
          o = fmaxf(o, dppf<0xB1>(o));
          o = fmaxf(o, dppf<0x4E>(o));
          o = fmaxf(o, dppf<0x141>(o));
          o = fmaxf(o, dppf<0x140>(o));
          acc[hf * 4 + mq][r] += fmaxf(o, 0.f);
        }
    }
  }
  if (nloc == 0) {
#pragma unroll
    for (int mt = 0; mt < 8; ++mt)
#pragma unroll
      for (int r = 0; r < 4; ++r)
        fstage[w][mt * 16 + grp * 4 + r] = acc[mt][r];
  }
  __syncthreads();
  if (tid < 128) {
    float4 v = make_float4(fstage[0][tid], fstage[1][tid], fstage[2][tid], fstage[3][tid]);
    *(float4*)&out_feats[((size_t)(bt * C1 + tid)) * M + m0] = v;
  }
}

extern "C" void kernel_launch(void* const* d_in, const int* in_sizes, int n_in,
                              void* d_out, int out_size, void* d_ws, size_t ws_size,
                              hipStream_t stream) {
  const float* xyzs = (const float*)d_in[0];
  const float* feats = (const float*)d_in[1];
  const float* Wd = (const float*)d_in[2];
  const float* Wf = (const float*)d_in[3];
  const float* W1 = (const float*)d_in[4];
  float* out_xyz = (float*)d_out;                            // (B,8,M,3)
  float* out_feats = (float*)d_out + (size_t)B * T * M * 3;  // (B,8,C1,M)
  char* ws = (char*)d_ws;
  float* RFF = (float*)ws;                                          // 33.55 MB
  int* idxbuf = (int*)(ws + (size_t)B * T * N * 64 * 4);            // 12.58 MB
  char* tail = ws + (size_t)B * T * N * 64 * 4 + (size_t)B * T * 3 * M * KNN * 4;
  float* WfT = (float*)tail;                                        // 16 KB
  unsigned short* w1hi = (unsigned short*)(tail + 16384);           // 16 KB
  unsigned short* w1lo = (unsigned short*)(tail + 32768);           // 16 KB
  float* wsD = (float*)(tail + 49152);                              // 512 KB
  int* wsLast = (int*)(tail + 49152 + (size_t)B * T * N * 4);       // 128 B
  prep_wft<<<16, 256, 0, stream>>>(Wf, WfT);
  prep_w1frag<<<32, 256, 0, stream>>>(W1, w1hi, w1lo);
  fps_rff_a_kernel<<<32 + 2048, 256, 0, stream>>>(xyzs, out_xyz, feats, WfT, RFF, wsD, wsLast);
  fps_b_kernel<<<32, 256, 0, stream>>>(xyzs, out_xyz, wsD, wsLast);
  ballq_kernel<<<(B * T * 3 * M) / 4, 256, 0, stream>>>(xyzs, out_xyz, idxbuf);
  mlp_kernel<<<(B * T * M) / 4, 256, 0, stream>>>(xyzs, RFF, w1hi, w1lo, Wd, out_xyz,
                                                  idxbuf, out_feats);
}

// Round 9
// 1231.568 us; speedup vs baseline: 1.5350x; 1.5350x over previous
//
#include <hip/hip_runtime.h>

constexpr int B = 4, T = 8, N = 4096, C0 = 64, C1 = 128;
constexpr int M = 1024, KNN = 32;

typedef __attribute__((ext_vector_type(8))) short short8;
typedef __attribute__((ext_vector_type(4))) float f32x4;

__device__ __forceinline__ unsigned short f2bf(float x) {
  unsigned u = __float_as_uint(x);
  u = u + 0x7FFFu + ((u >> 16) & 1u);
  return (unsigned short)(u >> 16);
}
__device__ __forceinline__ float bf2f(unsigned short h) {
  return __uint_as_float((unsigned)h << 16);
}

template <int CTRL>
__device__ __forceinline__ float dppf(float x) {
  return __int_as_float(__builtin_amdgcn_update_dpp(0, __float_as_int(x), CTRL, 0xF, 0xF, true));
}
template <int CTRL>
__device__ __forceinline__ int dppi(int x) {
  return __builtin_amdgcn_update_dpp(0, x, CTRL, 0xF, 0xF, true);
}
template <int CTRL>
__device__ __forceinline__ unsigned long long dppu64(unsigned long long x) {
  unsigned lo = (unsigned)dppi<CTRL>((int)(unsigned)x);
  unsigned hi = (unsigned)dppi<CTRL>((int)(unsigned)(x >> 32));
  return ((unsigned long long)hi << 32) | lo;
}
__device__ __forceinline__ void kmerge(unsigned long long& a, unsigned long long b) {
  if (b > a) a = b;
}
__device__ __forceinline__ unsigned long long kmax(unsigned long long a, unsigned long long b) {
  return b > a ? b : a;
}

// ---------------- prep: WfT[c][o] = Wf[o][c] --------------------------------
__global__ __launch_bounds__(256) void prep_wft(const float* __restrict__ Wf,
                                                float* __restrict__ WfT) {
  int t = blockIdx.x * 256 + threadIdx.x;
  if (t < 64 * 64) WfT[t] = Wf[(t & 63) * 64 + (t >> 6)];
}

// ---------------- prep: W1 -> MFMA A-fragment-ordered bf16 hi/lo ------------
__global__ __launch_bounds__(256) void prep_w1frag(const float* __restrict__ W1,
                                                   unsigned short* __restrict__ w1hi,
                                                   unsigned short* __restrict__ w1lo) {
  int t = blockIdx.x * 256 + threadIdx.x;
  if (t >= 8192) return;
  int j = t & 7, lane = (t >> 3) & 63, mt = (t >> 9) & 7, kt = t >> 12;
  int row = mt * 16 + (lane & 15);
  int k = kt * 32 + (lane >> 4) * 8 + j;
  float v = W1[row * 64 + k];
  unsigned short hi = f2bf(v);
  w1hi[t] = hi;
  w1lo[t] = f2bf(v - bf2f(hi));
}

// ---------------- fused fps (blocks 0-31) + rff-bf16 (blocks 32-2079) -------
__device__ void fps_body(char* smem, const float* __restrict__ xyz,
                         float* __restrict__ out_xyz, int bt) {
  float4* P4 = (float4*)smem;                                              // 64 KB
  int* pick_l = (int*)(smem + 65536);                                      // 4 KB
  unsigned long long* wslot = (unsigned long long*)(smem + 65536 + 4096);  // 256 B
  const float* p = xyz + (size_t)bt * N * 3;
  int tid = threadIdx.x;
  int lane = tid & 63, w = tid >> 6;
  for (int i = tid; i < N; i += 256)
    P4[i] = make_float4(p[i * 3 + 0], p[i * 3 + 1], p[i * 3 + 2], 0.f);
  if (tid == 0) pick_l[0] = 0;
  __syncthreads();
  float X[16], Y[16], Z[16], D[16];
  unsigned inv[16];
#pragma unroll
  for (int j = 0; j < 16; ++j) {
    float4 v = P4[j * 256 + tid];  // consecutive lanes -> consecutive banks
    X[j] = v.x; Y[j] = v.y; Z[j] = v.z;
    D[j] = 1e10f;
    inv[j] = ~(unsigned)(j * 256 + tid);
  }
  int lidx = 0;
  for (int s = 1; s < M; ++s) {
    float4 lp = P4[lidx];  // broadcast ds_read_b128
    unsigned long long k[16];
#pragma unroll
    for (int j = 0; j < 16; ++j) {
      float dx = __fsub_rn(X[j], lp.x);
      float dy = __fsub_rn(Y[j], lp.y);
      float dz = __fsub_rn(Z[j], lp.z);
      float d = __fadd_rn(__fadd_rn(__fmul_rn(dx, dx), __fmul_rn(dy, dy)), __fmul_rn(dz, dz));
      float nd = fminf(D[j], d);
      D[j] = nd;
      k[j] = ((unsigned long long)__float_as_uint(nd) << 32) | inv[j];
    }
#pragma unroll
    for (int st = 8; st >= 1; st >>= 1)
#pragma unroll
      for (int j = 0; j < st; ++j) kmerge(k[j], k[j + st]);
    unsigned long long best = k[0];
    kmerge(best, dppu64<0xB1>(best));
    kmerge(best, dppu64<0x4E>(best));
    kmerge(best, dppu64<0x141>(best));
    kmerge(best, dppu64<0x140>(best));
    int buf = s & 1;
    if ((lane & 15) == 0) wslot[buf * 16 + w * 4 + (lane >> 4)] = best;
    __syncthreads();
    const ulonglong2* ws2 = (const ulonglong2*)&wslot[buf * 16];
    ulonglong2 a0 = ws2[0], a1 = ws2[1], a2 = ws2[2], a3 = ws2[3];
    ulonglong2 a4 = ws2[4], a5 = ws2[5], a6 = ws2[6], a7 = ws2[7];
    unsigned long long t0 = kmax(kmax(a0.x, a0.y), kmax(a1.x, a1.y));
    unsigned long long t1 = kmax(kmax(a2.x, a2.y), kmax(a3.x, a3.y));
    unsigned long long t2 = kmax(kmax(a4.x, a4.y), kmax(a5.x, a5.y));
    unsigned long long t3 = kmax(kmax(a6.x, a6.y), kmax(a7.x, a7.y));
    unsigned long long g = kmax(kmax(t0, t1), kmax(t2, t3));
    lidx = (int)(~(unsigned)g);
    if (tid == 0) pick_l[s] = lidx;
  }
  __syncthreads();
  float* outp = out_xyz + (size_t)bt * M * 3;
  for (int mm = tid; mm < M; mm += 256) {
    float4 v = P4[pick_l[mm]];
    outp[mm * 3 + 0] = v.x;
    outp[mm * 3 + 1] = v.y;
    outp[mm * 3 + 2] = v.z;
  }
}

__device__ void rff_body(char* smem, const float* __restrict__ f,
                         const float* __restrict__ WfT, unsigned short* __restrict__ RFFh,
                         int rid) {
  float (*tile)[65] = (float (*)[65])smem;  // 64x65 f32 = 16.6 KB
  int bt = rid >> 6;
  int n0 = (rid & 63) * 64;
  const float* src = f + (size_t)bt * C0 * N;
  int tx = threadIdx.x & 63, ty = threadIdx.x >> 6;
  for (int r = ty; r < 64; r += 4)
    tile[r][tx] = src[(size_t)r * N + n0 + tx];
  __syncthreads();
  float acc[16];
#pragma unroll
  for (int oo = 0; oo < 16; ++oo) acc[oo] = 0.f;
  int obase = ty * 16;
#pragma unroll 4
  for (int c = 0; c < 64; ++c) {
    float fv = tile[c][tx];
    const float* wr = WfT + c * 64 + obase;
#pragma unroll
    for (int oo = 0; oo < 16; ++oo) acc[oo] = fmaf(fv, wr[oo], acc[oo]);
  }
  __syncthreads();
#pragma unroll
  for (int oo = 0; oo < 16; ++oo) tile[obase + oo][tx] = fmaxf(acc[oo], 0.f);
  __syncthreads();
  unsigned short* dst = RFFh + ((size_t)bt * N + n0) * 64;
  for (int r = ty; r < 64; r += 4)
    dst[(size_t)r * 64 + tx] = f2bf(tile[tx][r]);
}

__global__ __launch_bounds__(256) void fps_rff_kernel(const float* __restrict__ xyz,
                                                      float* __restrict__ out_xyz,
                                                      const float* __restrict__ feats,
                                                      const float* __restrict__ WfT,
                                                      unsigned short* __restrict__ RFFh) {
  __shared__ __align__(16) char smem[65536 + 4096 + 256];
  if (blockIdx.x < 32)
    fps_body(smem, xyz, out_xyz, blockIdx.x);
  else
    rff_body(smem, feats, WfT, RFFh, blockIdx.x - 32);
}

// ---------------- ball query: one wave per (b,t,di,m) -----------------------
__global__ __launch_bounds__(256) void ballq_kernel(const float* __restrict__ xyz,
                                                    const float* __restrict__ anchors,
                                                    int* __restrict__ idxbuf) {
  const float R2 = 0.04f;
  int w = threadIdx.x >> 6, lane = threadIdx.x & 63;
  int q = blockIdx.x * 4 + w;
  int m = q & (M - 1);
  int di = (q >> 10) % 3;
  int bt = q / (M * 3);
  int b = bt >> 3, t = bt & 7;
  int srct = t + di - 1;
  srct = srct < 0 ? 0 : (srct > 7 ? 7 : srct);
  const float* anc = anchors + ((size_t)(bt * M + m)) * 3;
  float ax = anc[0], ay = anc[1], az = anc[2];
  const float* pts = xyz + ((size_t)(b * T + srct)) * N * 3;
  int* outp = idxbuf + (size_t)q * KNN;
  int cnt = 0, first = 0;
  for (int c = 0; c < N / 64 && cnt < KNN; ++c) {
    int pi = c * 64 + lane;
    const float* pp = pts + (size_t)pi * 3;
    float dx = __fsub_rn(ax, pp[0]);
    float dy = __fsub_rn(ay, pp[1]);
    float dz = __fsub_rn(az, pp[2]);
    float d2 = __fadd_rn(__fadd_rn(__fmul_rn(dx, dx), __fmul_rn(dy, dy)), __fmul_rn(dz, dz));
    bool hit = d2 < R2;
    unsigned long long mask = __ballot(hit);
    if (cnt == 0 && mask) first = c * 64 + (int)__builtin_ctzll(mask);
    int prefix = (int)__popcll(mask & ((1ull << lane) - 1ull));
    int slot = cnt + prefix;
    if (hit && slot < KNN) outp[slot] = pi;
    cnt += (int)__popcll(mask);
  }
  int cntK = cnt < KNN ? cnt : KNN;
  int fill = (cnt == 0) ? 0 : first;
  if (lane < KNN && lane >= cntK) outp[lane] = fill;
}

// ---------------- fused gather(bf16) + dfeat + split-bf16 MFMA layer2 -------
// wave = anchor. bf16 RFF gather: one 128B line per row. XCD-aware block
// swizzle clusters same-bt anchors per XCD for L2/L3 row reuse.
__global__ __launch_bounds__(256) void mlp_kernel(const float* __restrict__ xyz,
                                                  const unsigned short* __restrict__ RFFh,
                                                  const unsigned short* __restrict__ w1hi,
                                                  const unsigned short* __restrict__ w1lo,
                                                  const float* __restrict__ Wd,
                                                  const float* __restrict__ anchors,
                                                  const int* __restrict__ idxbuf,
                                                  float* __restrict__ out_feats) {
  __shared__ unsigned short Ah[8192];
  __shared__ unsigned short Al[8192];
  __shared__ float wd_l[256];
  __shared__ float fstage[4][128];
  int tid = threadIdx.x;
  {
    uint4* dh = (uint4*)Ah;
    const uint4* sh = (const uint4*)w1hi;
    uint4* dl = (uint4*)Al;
    const uint4* sl = (const uint4*)w1lo;
    for (int i = tid; i < 1024; i += 256) { dh[i] = sh[i]; dl[i] = sl[i]; }
    wd_l[tid] = Wd[tid];
  }
  __syncthreads();
  int w = tid >> 6, lane = tid & 63;
  int nloc = lane & 15, grp = lane >> 4;
  // XCD-aware swizzle: 8192 blocks, 8 XCDs -> each XCD gets 1024 contiguous ids
  int bid = blockIdx.x;
  int swz = ((bid & 7) << 10) | (bid >> 3);
  int bt = swz >> 8;
  int m0 = (swz & 255) * 4;
  int m = m0 + w;
  int b = bt >> 3, t = bt & 7;
  int aoff = __builtin_amdgcn_readfirstlane(bt * M + m);
  float ax = anchors[(size_t)aoff * 3 + 0];
  float ay = anchors[(size_t)aoff * 3 + 1];
  float az = anchors[(size_t)aoff * 3 + 2];
  f32x4 acc[8];
#pragma unroll
  for (int mt = 0; mt < 8; ++mt) acc[mt] = (f32x4){0.f, 0.f, 0.f, 0.f};

  for (int di = 0; di < 3; ++di) {
    int srct = t + di - 1;
    srct = srct < 0 ? 0 : (srct > 7 ? 7 : srct);
    const unsigned short* rf = RFFh + ((size_t)(b * T + srct)) * N * 64;
    const float* pts = xyz + ((size_t)(b * T + srct)) * N * 3;
    const int* ip = idxbuf + ((size_t)((bt * 3 + di) * M + m)) * KNN;
    int n0 = ip[nloc], n1 = ip[16 + nloc];
    short8 g0[2], g1[2];  // [kt] bf16 rff fragments
#pragma unroll
    for (int kt = 0; kt < 2; ++kt) {
      g0[kt] = *(const short8*)(rf + (size_t)n0 * 64 + kt * 32 + grp * 8);
      g1[kt] = *(const short8*)(rf + (size_t)n1 * 64 + kt * 32 + grp * 8);
    }
    float dx0 = pts[n0 * 3 + 0] - ax, dy0 = pts[n0 * 3 + 1] - ay, dz0 = pts[n0 * 3 + 2] - az;
    float dx1 = pts[n1 * 3 + 0] - ax, dy1 = pts[n1 * 3 + 1] - ay, dz1 = pts[n1 * 3 + 2] - az;
    float tv = (float)(di - 1);
    short8 Bh[2][2], Bl[2][2];  // [kt][nt]
#pragma unroll
    for (int kt = 0; kt < 2; ++kt) {
      short8 bh0, bl0, bh1, bl1;
#pragma unroll
      for (int j = 0; j < 8; ++j) {
        int ch = kt * 32 + grp * 8 + j;
        float4 wr = *(const float4*)&wd_l[ch * 4];
        float dd0 = fmaf(dx0, wr.x, fmaf(dy0, wr.y, fmaf(dz0, wr.z, tv * wr.w)));
        float dd1 = fmaf(dx1, wr.x, fmaf(dy1, wr.y, fmaf(dz1, wr.z, tv * wr.w)));
        float h0 = bf2f((unsigned short)g0[kt][j]) + fmaxf(dd0, 0.f);
        float h1 = bf2f((unsigned short)g1[kt][j]) + fmaxf(dd1, 0.f);
        unsigned short hi0 = f2bf(h0);
        bh0[j] = (short)hi0;
        bl0[j] = (short)f2bf(h0 - bf2f(hi0));
        unsigned short hi1 = f2bf(h1);
        bh1[j] = (short)hi1;
        bl1[j] = (short)f2bf(h1 - bf2f(hi1));
      }
      Bh[kt][0] = bh0; Bl[kt][0] = bl0;
      Bh[kt][1] = bh1; Bl[kt][1] = bl1;
    }
#pragma unroll
    for (int hf = 0; hf < 2; ++hf) {
      f32x4 c[4][2];
#pragma unroll
      for (int mq = 0; mq < 4; ++mq) {
        c[mq][0] = (f32x4){0.f, 0.f, 0.f, 0.f};
        c[mq][1] = (f32x4){0.f, 0.f, 0.f, 0.f};
      }
#pragma unroll
      for (int kt = 0; kt < 2; ++kt) {
#pragma unroll
        for (int mq = 0; mq < 4; ++mq) {
          int mt = hf * 4 + mq;
          int fo = ((kt * 8 + mt) * 64 + lane) * 8;
          short8 ahf = *(const short8*)&Ah[fo];
          short8 alf = *(const short8*)&Al[fo];
          c[mq][0] = __builtin_amdgcn_mfma_f32_16x16x32_bf16(ahf, Bh[kt][0], c[mq][0], 0, 0, 0);
          c[mq][0] = __builtin_amdgcn_mfma_f32_16x16x32_bf16(ahf, Bl[kt][0], c[mq][0], 0, 0, 0);
          c[mq][0] = __builtin_amdgcn_mfma_f32_16x16x32_bf16(alf, Bh[kt][0], c[mq][0], 0, 0, 0);
          c[mq][1] = __builtin_amdgcn_mfma_f32_16x16x32_bf16(ahf, Bh[kt][1], c[mq][1], 0, 0, 0);
          c[mq][1] = __builtin_amdgcn_mfma_f32_16x16x32_bf16(ahf, Bl[kt][1], c[mq][1], 0, 0, 0);
          c[mq][1] = __builtin_amdgcn_mfma_f32_16x16x32_bf16(alf, Bh[kt][1], c[mq][1], 0, 0, 0);
        }
      }
#pragma unroll
      for (int mq = 0; mq < 4; ++mq)
#pragma unroll
        for (int r = 0; r < 4; ++r) {
          float o = fmaxf(c[mq][0][r], c[mq][1][r]);
          o = fmaxf(o, dppf<0xB1>(o));
          o = fmaxf(o, dppf<0x4E>(o));
          o = fmaxf(o, dppf<0x141>(o));
          o = fmaxf(o, dppf<0x140>(o));
          acc[hf * 4 + mq][r] += fmaxf(o, 0.f);
        }
    }
  }
  if (nloc == 0) {
#pragma unroll
    for (int mt = 0; mt < 8; ++mt)
#pragma unroll
      for (int r = 0; r < 4; ++r)
        fstage[w][mt * 16 + grp * 4 + r] = acc[mt][r];
  }
  __syncthreads();
  if (tid < 128) {
    float4 v = make_float4(fstage[0][tid], fstage[1][tid], fstage[2][tid], fstage[3][tid]);
    *(float4*)&out_feats[((size_t)(bt * C1 + tid)) * M + m0] = v;
  }
}

extern "C" void kernel_launch(void* const* d_in, const int* in_sizes, int n_in,
                              void* d_out, int out_size, void* d_ws, size_t ws_size,
                              hipStream_t stream) {
  const float* xyzs = (const float*)d_in[0];
  const float* feats = (const float*)d_in[1];
  const float* Wd = (const float*)d_in[2];
  const float* Wf = (const float*)d_in[3];
  const float* W1 = (const float*)d_in[4];
  float* out_xyz = (float*)d_out;                            // (B,8,M,3)
  float* out_feats = (float*)d_out + (size_t)B * T * M * 3;  // (B,8,C1,M)
  char* ws = (char*)d_ws;
  unsigned short* RFFh = (unsigned short*)ws;                       // 16.78 MB used
  int* idxbuf = (int*)(ws + (size_t)B * T * N * 64 * 4);            // 12.58 MB
  char* tail = ws + (size_t)B * T * N * 64 * 4 + (size_t)B * T * 3 * M * KNN * 4;
  float* WfT = (float*)tail;                                        // 16 KB
  unsigned short* w1hi = (unsigned short*)(tail + 16384);           // 16 KB
  unsigned short* w1lo = (unsigned short*)(tail + 32768);           // 16 KB
  prep_wft<<<16, 256, 0, stream>>>(Wf, WfT);
  prep_w1frag<<<32, 256, 0, stream>>>(W1, w1hi, w1lo);
  fps_rff_kernel<<<32 + 2048, 256, 0, stream>>>(xyzs, out_xyz, feats, WfT, RFFh);
  ballq_kernel<<<(B * T * 3 * M) / 4, 256, 0, stream>>>(xyzs, out_xyz, idxbuf);
  mlp_kernel<<<(B * T * M) / 4, 256, 0, stream>>>(xyzs, RFFh, w1hi, w1lo, Wd, out_xyz,
                                                  idxbuf, out_feats);
}

// Round 10
// 1056.485 us; speedup vs baseline: 1.7894x; 1.1657x over previous
//
#include <hip/hip_runtime.h>
#include <hip/hip_bf16.h>

constexpr int B = 4, T = 8, N = 4096, C0 = 64, C1 = 128;
constexpr int M = 1024, KNN = 32;

typedef __attribute__((ext_vector_type(8))) short short8;
typedef __attribute__((ext_vector_type(4))) float f32x4;

__device__ __forceinline__ unsigned short f2bf(float x) {
  unsigned u = __float_as_uint(x);
  u = u + 0x7FFFu + ((u >> 16) & 1u);
  return (unsigned short)(u >> 16);
}
__device__ __forceinline__ float bf2f(unsigned short h) {
  return __uint_as_float((unsigned)h << 16);
}
__device__ __forceinline__ short f2bf_rn(float x) {
  union { __hip_bfloat16 b; unsigned short u; } v;
  v.b = __float2bfloat16(x);
  return (short)v.u;
}

template <int CTRL>
__device__ __forceinline__ float dppf(float x) {
  return __int_as_float(__builtin_amdgcn_update_dpp(0, __float_as_int(x), CTRL, 0xF, 0xF, true));
}
template <int CTRL>
__device__ __forceinline__ int dppi(int x) {
  return __builtin_amdgcn_update_dpp(0, x, CTRL, 0xF, 0xF, true);
}
template <int CTRL>
__device__ __forceinline__ unsigned long long dppu64(unsigned long long x) {
  unsigned lo = (unsigned)dppi<CTRL>((int)(unsigned)x);
  unsigned hi = (unsigned)dppi<CTRL>((int)(unsigned)(x >> 32));
  return ((unsigned long long)hi << 32) | lo;
}
__device__ __forceinline__ void kmerge(unsigned long long& a, unsigned long long b) {
  if (b > a) a = b;
}
__device__ __forceinline__ unsigned long long kmax(unsigned long long a, unsigned long long b) {
  return b > a ? b : a;
}

// ---------------- prep: WfT[c][o] = Wf[o][c] --------------------------------
__global__ __launch_bounds__(256) void prep_wft(const float* __restrict__ Wf,
                                                float* __restrict__ WfT) {
  int t = blockIdx.x * 256 + threadIdx.x;
  if (t < 64 * 64) WfT[t] = Wf[(t & 63) * 64 + (t >> 6)];
}

// ---------------- prep: W1 -> MFMA A-fragment-ordered bf16 hi/lo ------------
__global__ __launch_bounds__(256) void prep_w1frag(const float* __restrict__ W1,
                                                   unsigned short* __restrict__ w1hi,
                                                   unsigned short* __restrict__ w1lo) {
  int t = blockIdx.x * 256 + threadIdx.x;
  if (t >= 8192) return;
  int j = t & 7, lane = (t >> 3) & 63, mt = (t >> 9) & 7, kt = t >> 12;
  int row = mt * 16 + (lane & 15);
  int k = kt * 32 + (lane >> 4) * 8 + j;
  float v = W1[row * 64 + k];
  unsigned short hi = f2bf(v);
  w1hi[t] = hi;
  w1lo[t] = f2bf(v - bf2f(hi));
}

// ---------------- fused fps (blocks 0-31) + rff-bf16 (blocks 32-2079) -------
__device__ void fps_body(char* smem, const float* __restrict__ xyz,
                         float* __restrict__ out_xyz, int bt) {
  float4* P4 = (float4*)smem;                                              // 64 KB
  int* pick_l = (int*)(smem + 65536);                                      // 4 KB
  unsigned long long* wslot = (unsigned long long*)(smem + 65536 + 4096);  // 256 B
  const float* p = xyz + (size_t)bt * N * 3;
  int tid = threadIdx.x;
  int lane = tid & 63, w = tid >> 6;
  for (int i = tid; i < N; i += 256)
    P4[i] = make_float4(p[i * 3 + 0], p[i * 3 + 1], p[i * 3 + 2], 0.f);
  if (tid == 0) pick_l[0] = 0;
  __syncthreads();
  float X[16], Y[16], Z[16], D[16];
  unsigned inv[16];
#pragma unroll
  for (int j = 0; j < 16; ++j) {
    float4 v = P4[j * 256 + tid];  // consecutive lanes -> consecutive banks
    X[j] = v.x; Y[j] = v.y; Z[j] = v.z;
    D[j] = 1e10f;
    inv[j] = ~(unsigned)(j * 256 + tid);
  }
  int lidx = 0;
  for (int s = 1; s < M; ++s) {
    float4 lp = P4[lidx];  // broadcast ds_read_b128
    unsigned long long k[16];
#pragma unroll
    for (int j = 0; j < 16; ++j) {
      float dx = __fsub_rn(X[j], lp.x);
      float dy = __fsub_rn(Y[j], lp.y);
      float dz = __fsub_rn(Z[j], lp.z);
      float d = __fadd_rn(__fadd_rn(__fmul_rn(dx, dx), __fmul_rn(dy, dy)), __fmul_rn(dz, dz));
      float nd = fminf(D[j], d);
      D[j] = nd;
      k[j] = ((unsigned long long)__float_as_uint(nd) << 32) | inv[j];
    }
#pragma unroll
    for (int st = 8; st >= 1; st >>= 1)
#pragma unroll
      for (int j = 0; j < st; ++j) kmerge(k[j], k[j + st]);
    unsigned long long best = k[0];
    kmerge(best, dppu64<0xB1>(best));
    kmerge(best, dppu64<0x4E>(best));
    kmerge(best, dppu64<0x141>(best));
    kmerge(best, dppu64<0x140>(best));
    int buf = s & 1;
    if ((lane & 15) == 0) wslot[buf * 16 + w * 4 + (lane >> 4)] = best;
    __syncthreads();
    const ulonglong2* ws2 = (const ulonglong2*)&wslot[buf * 16];
    ulonglong2 a0 = ws2[0], a1 = ws2[1], a2 = ws2[2], a3 = ws2[3];
    ulonglong2 a4 = ws2[4], a5 = ws2[5], a6 = ws2[6], a7 = ws2[7];
    unsigned long long t0 = kmax(kmax(a0.x, a0.y), kmax(a1.x, a1.y));
    unsigned long long t1 = kmax(kmax(a2.x, a2.y), kmax(a3.x, a3.y));
    unsigned long long t2 = kmax(kmax(a4.x, a4.y), kmax(a5.x, a5.y));
    unsigned long long t3 = kmax(kmax(a6.x, a6.y), kmax(a7.x, a7.y));
    unsigned long long g = kmax(kmax(t0, t1), kmax(t2, t3));
    lidx = (int)(~(unsigned)g);
    if (tid == 0) pick_l[s] = lidx;
  }
  __syncthreads();
  float* outp = out_xyz + (size_t)bt * M * 3;
  for (int mm = tid; mm < M; mm += 256) {
    float4 v = P4[pick_l[mm]];
    outp[mm * 3 + 0] = v.x;
    outp[mm * 3 + 1] = v.y;
    outp[mm * 3 + 2] = v.z;
  }
}

__device__ void rff_body(char* smem, const float* __restrict__ f,
                         const float* __restrict__ WfT, unsigned short* __restrict__ RFFh,
                         int rid) {
  float (*tile)[65] = (float (*)[65])smem;  // 64x65 f32 = 16.6 KB
  int bt = rid >> 6;
  int n0 = (rid & 63) * 64;
  const float* src = f + (size_t)bt * C0 * N;
  int tx = threadIdx.x & 63, ty = threadIdx.x >> 6;
  for (int r = ty; r < 64; r += 4)
    tile[r][tx] = src[(size_t)r * N + n0 + tx];
  __syncthreads();
  float acc[16];
#pragma unroll
  for (int oo = 0; oo < 16; ++oo) acc[oo] = 0.f;
  int obase = ty * 16;
#pragma unroll 4
  for (int c = 0; c < 64; ++c) {
    float fv = tile[c][tx];
    const float* wr = WfT + c * 64 + obase;
#pragma unroll
    for (int oo = 0; oo < 16; ++oo) acc[oo] = fmaf(fv, wr[oo], acc[oo]);
  }
  __syncthreads();
#pragma unroll
  for (int oo = 0; oo < 16; ++oo) tile[obase + oo][tx] = fmaxf(acc[oo], 0.f);
  __syncthreads();
  unsigned short* dst = RFFh + ((size_t)bt * N + n0) * 64;
  for (int r = ty; r < 64; r += 4)
    dst[(size_t)r * 64 + tx] = f2bf(tile[tx][r]);
}

__global__ __launch_bounds__(256) void fps_rff_kernel(const float* __restrict__ xyz,
                                                      float* __restrict__ out_xyz,
                                                      const float* __restrict__ feats,
                                                      const float* __restrict__ WfT,
                                                      unsigned short* __restrict__ RFFh) {
  __shared__ __align__(16) char smem[65536 + 4096 + 256];
  if (blockIdx.x < 32)
    fps_body(smem, xyz, out_xyz, blockIdx.x);
  else
    rff_body(smem, feats, WfT, RFFh, blockIdx.x - 32);
}

// ---------------- ball query: one wave per (b,t,di,m) -----------------------
__global__ __launch_bounds__(256) void ballq_kernel(const float* __restrict__ xyz,
                                                    const float* __restrict__ anchors,
                                                    int* __restrict__ idxbuf) {
  const float R2 = 0.04f;
  int w = threadIdx.x >> 6, lane = threadIdx.x & 63;
  int q = blockIdx.x * 4 + w;
  int m = q & (M - 1);
  int di = (q >> 10) % 3;
  int bt = q / (M * 3);
  int b = bt >> 3, t = bt & 7;
  int srct = t + di - 1;
  srct = srct < 0 ? 0 : (srct > 7 ? 7 : srct);
  const float* anc = anchors + ((size_t)(bt * M + m)) * 3;
  float ax = anc[0], ay = anc[1], az = anc[2];
  const float* pts = xyz + ((size_t)(b * T + srct)) * N * 3;
  int* outp = idxbuf + (size_t)q * KNN;
  int cnt = 0, first = 0;
  for (int c = 0; c < N / 64 && cnt < KNN; ++c) {
    int pi = c * 64 + lane;
    const float* pp = pts + (size_t)pi * 3;
    float dx = __fsub_rn(ax, pp[0]);
    float dy = __fsub_rn(ay, pp[1]);
    float dz = __fsub_rn(az, pp[2]);
    float d2 = __fadd_rn(__fadd_rn(__fmul_rn(dx, dx), __fmul_rn(dy, dy)), __fmul_rn(dz, dz));
    bool hit = d2 < R2;
    unsigned long long mask = __ballot(hit);
    if (cnt == 0 && mask) first = c * 64 + (int)__builtin_ctzll(mask);
    int prefix = (int)__popcll(mask & ((1ull << lane) - 1ull));
    int slot = cnt + prefix;
    if (hit && slot < KNN) outp[slot] = pi;
    cnt += (int)__popcll(mask);
  }
  int cntK = cnt < KNN ? cnt : KNN;
  int fill = (cnt == 0) ? 0 : first;
  if (lane < KNN && lane >= cntK) outp[lane] = fill;
}

// ---------------- fused gather(bf16) + dfeat + MFMA layer2 (v4) -------------
// wave = anchor; B operand single bf16 (W1 keeps hi+lo): 64 MFMA/di, lean
// B-build via __float2bfloat16 (cvt_pk). di-pipelined register prefetch.
__global__ __launch_bounds__(256) void mlp_kernel(const float* __restrict__ xyz,
                                                  const unsigned short* __restrict__ RFFh,
                                                  const unsigned short* __restrict__ w1hi,
                                                  const unsigned short* __restrict__ w1lo,
                                                  const float* __restrict__ Wd,
                                                  const float* __restrict__ anchors,
                                                  const int* __restrict__ idxbuf,
                                                  float* __restrict__ out_feats) {
  __shared__ unsigned short Ah[8192];
  __shared__ unsigned short Al[8192];
  __shared__ float wd_l[256];
  __shared__ float fstage[4][128];
  int tid = threadIdx.x;
  {
    uint4* dh = (uint4*)Ah;
    const uint4* sh = (const uint4*)w1hi;
    uint4* dl = (uint4*)Al;
    const uint4* sl = (const uint4*)w1lo;
    for (int i = tid; i < 1024; i += 256) { dh[i] = sh[i]; dl[i] = sl[i]; }
    wd_l[tid] = Wd[tid];
  }
  __syncthreads();
  int w = tid >> 6, lane = tid & 63;
  int nloc = lane & 15, grp = lane >> 4;
  // XCD-aware swizzle: 8192 blocks, 8 XCDs -> each XCD gets 1024 contiguous ids
  int bid = blockIdx.x;
  int swz = ((bid & 7) << 10) | (bid >> 3);
  int bt = swz >> 8;
  int m0 = (swz & 255) * 4;
  int m = m0 + w;
  int b = bt >> 3, t = bt & 7;
  int aoff = __builtin_amdgcn_readfirstlane(bt * M + m);
  float ax = anchors[(size_t)aoff * 3 + 0];
  float ay = anchors[(size_t)aoff * 3 + 1];
  float az = anchors[(size_t)aoff * 3 + 2];
  f32x4 acc[8];
#pragma unroll
  for (int mt = 0; mt < 8; ++mt) acc[mt] = (f32x4){0.f, 0.f, 0.f, 0.f};

  short8 pg0[2][2], pg1[2][2];  // [buf][kt] bf16 rff fragments
  float ppx[2][2], ppy[2][2], ppz[2][2];

#define MLOADP(BUF, DI)                                                        \
  {                                                                            \
    int srct = t + (DI)-1;                                                     \
    srct = srct < 0 ? 0 : (srct > 7 ? 7 : srct);                               \
    const unsigned short* rf = RFFh + ((size_t)(b * T + srct)) * N * 64;       \
    const float* pts = xyz + ((size_t)(b * T + srct)) * N * 3;                 \
    const int* ip = idxbuf + ((size_t)((bt * 3 + (DI)) * M + m)) * KNN;        \
    int n0 = ip[nloc], n1 = ip[16 + nloc];                                     \
    _Pragma("unroll") for (int kt = 0; kt < 2; ++kt) {                         \
      pg0[BUF][kt] = *(const short8*)(rf + (size_t)n0 * 64 + kt * 32 + grp * 8); \
      pg1[BUF][kt] = *(const short8*)(rf + (size_t)n1 * 64 + kt * 32 + grp * 8); \
    }                                                                          \
    ppx[BUF][0] = pts[n0 * 3 + 0];                                             \
    ppy[BUF][0] = pts[n0 * 3 + 1];                                             \
    ppz[BUF][0] = pts[n0 * 3 + 2];                                             \
    ppx[BUF][1] = pts[n1 * 3 + 0];                                             \
    ppy[BUF][1] = pts[n1 * 3 + 1];                                             \
    ppz[BUF][1] = pts[n1 * 3 + 2];                                             \
  }

#define MCOMPUTE(BUF, DI)                                                      \
  {                                                                            \
    int zro = 0;                                                               \
    asm volatile("" : "+v"(zro));                                              \
    const unsigned short* AhO = Ah + zro;                                      \
    const unsigned short* AlO = Al + zro;                                      \
    const float* wdO = (const float*)wd_l + zro;                               \
    float tvv = (float)((DI)-1);                                               \
    float dx0 = ppx[BUF][0] - ax, dy0 = ppy[BUF][0] - ay, dz0 = ppz[BUF][0] - az; \
    float dx1 = ppx[BUF][1] - ax, dy1 = ppy[BUF][1] - ay, dz1 = ppz[BUF][1] - az; \
    short8 Bh[2][2]; /* [kt][nt] */                                            \
    _Pragma("unroll") for (int kt = 0; kt < 2; ++kt) {                         \
      short8 bh0, bh1;                                                         \
      _Pragma("unroll") for (int j = 0; j < 8; ++j) {                          \
        int ch = kt * 32 + grp * 8 + j;                                        \
        float4 wr = *(const float4*)&wdO[ch * 4];                              \
        float dd0 = fmaf(dx0, wr.x, fmaf(dy0, wr.y, fmaf(dz0, wr.z, tvv * wr.w))); \
        float dd1 = fmaf(dx1, wr.x, fmaf(dy1, wr.y, fmaf(dz1, wr.z, tvv * wr.w))); \
        float h0 = bf2f((unsigned short)pg0[BUF][kt][j]) + fmaxf(dd0, 0.f);    \
        float h1 = bf2f((unsigned short)pg1[BUF][kt][j]) + fmaxf(dd1, 0.f);    \
        bh0[j] = f2bf_rn(h0);                                                  \
        bh1[j] = f2bf_rn(h1);                                                  \
      }                                                                        \
      Bh[kt][0] = bh0;                                                         \
      Bh[kt][1] = bh1;                                                         \
    }                                                                          \
    _Pragma("unroll") for (int hf = 0; hf < 2; ++hf) {                         \
      f32x4 c[4][2];                                                           \
      _Pragma("unroll") for (int mq = 0; mq < 4; ++mq) {                       \
        c[mq][0] = (f32x4){0.f, 0.f, 0.f, 0.f};                                \
        c[mq][1] = (f32x4){0.f, 0.f, 0.f, 0.f};                                \
      }                                                                        \
      _Pragma("unroll") for (int kt = 0; kt < 2; ++kt) {                       \
        _Pragma("unroll") for (int mq = 0; mq < 4; ++mq) {                     \
          int fo = ((kt * 8 + hf * 4 + mq) * 64 + lane) * 8;                   \
          short8 ahf = *(const short8*)&AhO[fo];                               \
          short8 alf = *(const short8*)&AlO[fo];                               \
          c[mq][0] =                                                           \
              __builtin_amdgcn_mfma_f32_16x16x32_bf16(ahf, Bh[kt][0], c[mq][0], 0, 0, 0); \
          c[mq][0] =                                                           \
              __builtin_amdgcn_mfma_f32_16x16x32_bf16(alf, Bh[kt][0], c[mq][0], 0, 0, 0); \
          c[mq][1] =                                                           \
              __builtin_amdgcn_mfma_f32_16x16x32_bf16(ahf, Bh[kt][1], c[mq][1], 0, 0, 0); \
          c[mq][1] =                                                           \
              __builtin_amdgcn_mfma_f32_16x16x32_bf16(alf, Bh[kt][1], c[mq][1], 0, 0, 0); \
        }                                                                      \
      }                                                                        \
      _Pragma("unroll") for (int mq = 0; mq < 4; ++mq)                         \
          _Pragma("unroll") for (int r = 0; r < 4; ++r) {                      \
        float o = fmaxf(c[mq][0][r], c[mq][1][r]);                             \
        o = fmaxf(o, dppf<0xB1>(o));                                           \
        o = fmaxf(o, dppf<0x4E>(o));                                           \
        o = fmaxf(o, dppf<0x141>(o));                                          \
        o = fmaxf(o, dppf<0x140>(o));                                          \
        acc[hf * 4 + mq][r] += fmaxf(o, 0.f);                                  \
      }                                                                        \
    }                                                                          \
  }

  MLOADP(0, 0)
  MLOADP(1, 1)
  MCOMPUTE(0, 0)
  MLOADP(0, 2)
  MCOMPUTE(1, 1)
  MCOMPUTE(0, 2)
#undef MLOADP
#undef MCOMPUTE

  if (nloc == 0) {
#pragma unroll
    for (int mt = 0; mt < 8; ++mt)
#pragma unroll
      for (int r = 0; r < 4; ++r)
        fstage[w][mt * 16 + grp * 4 + r] = acc[mt][r];
  }
  __syncthreads();
  if (tid < 128) {
    float4 v = make_float4(fstage[0][tid], fstage[1][tid], fstage[2][tid], fstage[3][tid]);
    *(float4*)&out_feats[((size_t)(bt * C1 + tid)) * M + m0] = v;
  }
}

extern "C" void kernel_launch(void* const* d_in, const int* in_sizes, int n_in,
                              void* d_out, int out_size, void* d_ws, size_t ws_size,
                              hipStream_t stream) {
  const float* xyzs = (const float*)d_in[0];
  const float* feats = (const float*)d_in[1];
  const float* Wd = (const float*)d_in[2];
  const float* Wf = (const float*)d_in[3];
  const float* W1 = (const float*)d_in[4];
  float* out_xyz = (float*)d_out;                            // (B,8,M,3)
  float* out_feats = (float*)d_out + (size_t)B * T * M * 3;  // (B,8,C1,M)
  char* ws = (char*)d_ws;
  unsigned short* RFFh = (unsigned short*)ws;                       // 16.78 MB used
  int* idxbuf = (int*)(ws + (size_t)B * T * N * 64 * 4);            // 12.58 MB
  char* tail = ws + (size_t)B * T * N * 64 * 4 + (size_t)B * T * 3 * M * KNN * 4;
  float* WfT = (float*)tail;                                        // 16 KB
  unsigned short* w1hi = (unsigned short*)(tail + 16384);           // 16 KB
  unsigned short* w1lo = (unsigned short*)(tail + 32768);           // 16 KB
  prep_wft<<<16, 256, 0, stream>>>(Wf, WfT);
  prep_w1frag<<<32, 256, 0, stream>>>(W1, w1hi, w1lo);
  fps_rff_kernel<<<32 + 2048, 256, 0, stream>>>(xyzs, out_xyz, feats, WfT, RFFh);
  ballq_kernel<<<(B * T * 3 * M) / 4, 256, 0, stream>>>(xyzs, out_xyz, idxbuf);
  mlp_kernel<<<(B * T * M) / 4, 256, 0, stream>>>(xyzs, RFFh, w1hi, w1lo, Wd, out_xyz,
                                                  idxbuf, out_feats);
}